// Round 1
// baseline (82.579 us; speedup 1.0000x reference)
//
#include <hip/hip_runtime.h>
#include <hip/hip_bf16.h>

#define D_IN 64
#define D_OUT 64
#define NS 8        // NUM_SPLINES
#define NK 12       // NUM_SPLINES + DEGREE + 1
#define KAN_EPS 1e-8f

// Grid: (BN/256, OUT_DIM). Each block owns one output channel o and 256 (b,n) rows.
__global__ __launch_bounds__(256)
void kan_kernel(const float* __restrict__ x,      // (4,512,64)
                const float* __restrict__ cp,     // (64,64,8)
                const float* __restrict__ knots,  // (64,64,12)
                const float* __restrict__ aw,     // (64,64,4)
                float* __restrict__ out)          // (4,64,512)
{
    __shared__ float s_t [D_IN][NK];   // knots row for this o
    __shared__ float s_r1[D_IN][NK];   // 1/(t[i+1]-t[i]+eps)
    __shared__ float s_r2[D_IN][NK];   // 1/(t[i+2]-t[i]+eps)
    __shared__ float s_r3[D_IN][NK];   // 1/(t[i+3]-t[i]+eps)
    __shared__ float s_cp[D_IN][NS];
    __shared__ float s_aw[D_IN][4];

    const int o   = blockIdx.y;
    const int tid = threadIdx.x;

    // ---- stage per-o tables into LDS ----
    for (int i = tid; i < D_IN * NK; i += 256) s_t[i / NK][i % NK] = knots[o * D_IN * NK + i];
    for (int i = tid; i < D_IN * NS; i += 256) s_cp[i / NS][i % NS] = cp[o * D_IN * NS + i];
    for (int i = tid; i < D_IN * 4;  i += 256) s_aw[i / 4][i % 4]   = aw[o * D_IN * 4 + i];
    __syncthreads();

    // reciprocal denominators (knot-only; removes all divides from the hot loop)
    for (int i = tid; i < D_IN * NK; i += 256) {
        int d = i / NK, j = i % NK;
        float t0 = s_t[d][j];
        s_r1[d][j] = (j + 1 < NK) ? 1.0f / (s_t[d][j + 1] - t0 + KAN_EPS) : 0.0f;
        s_r2[d][j] = (j + 2 < NK) ? 1.0f / (s_t[d][j + 2] - t0 + KAN_EPS) : 0.0f;
        s_r3[d][j] = (j + 3 < NK) ? 1.0f / (s_t[d][j + 3] - t0 + KAN_EPS) : 0.0f;
    }
    __syncthreads();

    const int bn = blockIdx.x * 256 + tid;          // 0..2047  (b*512+n)
    const float* __restrict__ xr = x + bn * D_IN;

    float spline_acc = 0.0f;
    float act_acc    = 0.0f;

    for (int d = 0; d < D_IN; ++d) {
        const float xv = xr[d];

        float t[NK];
        #pragma unroll
        for (int j = 0; j < NK; ++j) t[j] = s_t[d][j];

        // degree-0 basis
        float B[NK - 1];
        #pragma unroll
        for (int i = 0; i < NK - 1; ++i)
            B[i] = (xv >= t[i] && xv < t[i + 1]) ? 1.0f : 0.0f;

        // Cox-de Boor, k = 1
        #pragma unroll
        for (int i = 0; i < 10; ++i) {
            float c1 = (xv - t[i])     * s_r1[d][i];
            float c2 = (t[i + 2] - xv) * s_r1[d][i + 1];
            B[i] = c1 * B[i] + c2 * B[i + 1];
        }
        // k = 2
        #pragma unroll
        for (int i = 0; i < 9; ++i) {
            float c1 = (xv - t[i])     * s_r2[d][i];
            float c2 = (t[i + 3] - xv) * s_r2[d][i + 1];
            B[i] = c1 * B[i] + c2 * B[i + 1];
        }
        // k = 3
        #pragma unroll
        for (int i = 0; i < 8; ++i) {
            float c1 = (xv - t[i])     * s_r3[d][i];
            float c2 = (t[i + 4] - xv) * s_r3[d][i + 1];
            B[i] = c1 * B[i] + c2 * B[i + 1];
        }

        // spline dot with control points
        float sp = 0.0f;
        #pragma unroll
        for (int s = 0; s < NS; ++s) sp += B[s] * s_cp[d][s];
        spline_acc += sp;

        // activation mix: [relu, tanh, sigmoid, x]
        float xc = fminf(fmaxf(xv, -15.0f), 15.0f);   // guard exp overflow -> NaN
        float r  = fmaxf(xv, 0.0f);
        float e2 = __expf(2.0f * xc);
        float th = (e2 - 1.0f) / (e2 + 1.0f);
        float sg = 1.0f / (1.0f + __expf(-xc));
        act_acc += r  * s_aw[d][0] + th * s_aw[d][1]
                 + sg * s_aw[d][2] + xv * s_aw[d][3];
    }

    const int b = bn >> 9;          // /512
    const int n = bn & 511;         // %512
    out[((b * D_OUT + o) << 9) | n] = spline_acc + 0.1f * act_acc;
}

extern "C" void kernel_launch(void* const* d_in, const int* in_sizes, int n_in,
                              void* d_out, int out_size, void* d_ws, size_t ws_size,
                              hipStream_t stream) {
    const float* x     = (const float*)d_in[0];  // (4,512,64)
    const float* cp    = (const float*)d_in[1];  // (64,64,8)
    const float* knots = (const float*)d_in[2];  // (64,64,12)
    const float* aw    = (const float*)d_in[3];  // (64,64,4)
    float* out = (float*)d_out;                  // (4,64,512)

    dim3 grid(2048 / 256, D_OUT);   // (8, 64)
    dim3 block(256);
    kan_kernel<<<grid, block, 0, stream>>>(x, cp, knots, aw, out);
}

// Round 2
// 34.297 us; speedup vs baseline: 2.4078x; 2.4078x over previous
//
#include <hip/hip_runtime.h>
#include <hip/hip_bf16.h>

#define D_IN 64
#define D_OUT 64
#define NS 8        // NUM_SPLINES
#define NK 12       // knots per (o,d)
#define NREC 13     // interval records: idx = count(x >= t[j]) in [0,12]; 0 and 12 = out-of-range
#define KAN_EPS 1e-8f

// Precomputed per-(o,d,interval) cubic coefficients of
//   sum_s B3_s(x)*cp_s  + 0.1*(w3*x - w1)   (act identity + tanh-constant folded in)
// 64*64*13 records * 16B = 832 KB (L2-resident).
__device__ float4 g_rec[D_OUT * D_IN * NREC];

// ---------- polynomial helpers (degree-3 monomial coeffs) ----------
struct P4 { float c0, c1, c2, c3; };
__device__ inline P4 p_scal(P4 p, float s) { return {p.c0*s, p.c1*s, p.c2*s, p.c3*s}; }
__device__ inline P4 p_add(P4 a, P4 b) { return {a.c0+b.c0, a.c1+b.c1, a.c2+b.c2, a.c3+b.c3}; }
// (x - a) * p   (p.c3 must be 0 when degree grows to 3 — guaranteed by construction)
__device__ inline P4 p_mul_xma(P4 p, float a) { return {-a*p.c0, p.c0 - a*p.c1, p.c1 - a*p.c2, p.c2 - a*p.c3}; }
// (b - x) * p
__device__ inline P4 p_mul_bmx(P4 p, float b) { return {b*p.c0, b*p.c1 - p.c0, b*p.c2 - p.c1, b*p.c3 - p.c2}; }

// ---------- prep kernel: one thread per (o,d,iv13) ----------
__global__ void kan_prep(const float* __restrict__ cp,     // (64,64,8)
                         const float* __restrict__ knots,  // (64,64,12)
                         const float* __restrict__ aw)     // (64,64,4)
{
    int flat = blockIdx.x * 256 + threadIdx.x;
    if (flat >= D_OUT * D_IN * NREC) return;
    int iv13 = flat % NREC;       // 0..12
    int od   = flat / NREC;       // o*64 + d

    float t[NK];
    #pragma unroll
    for (int j = 0; j < NK; ++j) t[j] = knots[od * NK + j];

    // padded knot access (pad values arbitrary-but-finite & monotone; only feed
    // basis entries whose cp is forced to 0)
    auto tk = [&](int j) -> float {
        if (j < 0)  return t[0]  + (float)j;
        if (j > 11) return t[11] + (float)(j - 11);
        return t[j];
    };

    P4 sp = {0.f, 0.f, 0.f, 0.f};
    int iv = iv13 - 1;            // -1..11 ; valid intervals 0..10
    if (iv >= 0 && iv <= 10) {
        float tL0 = tk(iv),   tL1 = tk(iv-1), tL2 = tk(iv-2);
        float tR1 = tk(iv+1), tR2 = tk(iv+2), tR3 = tk(iv+3);
        float R1  = 1.f / (tR1 - tL0 + KAN_EPS);
        float R2a = 1.f / (tR1 - tL1 + KAN_EPS);
        float R2b = 1.f / (tR2 - tL0 + KAN_EPS);
        float R3a = 1.f / (tR1 - tL2 + KAN_EPS);
        float R3b = 1.f / (tR2 - tL1 + KAN_EPS);
        float R3c = 1.f / (tR3 - tL0 + KAN_EPS);

        // de Boor triangle, symbolic in x
        P4 N0 = {1.f, 0.f, 0.f, 0.f}, N1, N2, N3, t0, t1, t2, sv;
        // j = 1
        t0 = p_scal(N0, R1);
        N0 = p_mul_bmx(t0, tR1);
        N1 = p_mul_xma(t0, tL0);
        // j = 2
        t0 = p_scal(N0, R2a);
        N0 = p_mul_bmx(t0, tR1);
        sv = p_mul_xma(t0, tL1);
        t1 = p_scal(N1, R2b);
        N1 = p_add(sv, p_mul_bmx(t1, tR2));
        N2 = p_mul_xma(t1, tL0);
        // j = 3
        t0 = p_scal(N0, R3a);
        N0 = p_mul_bmx(t0, tR1);
        sv = p_mul_xma(t0, tL2);
        t1 = p_scal(N1, R3b);
        N1 = p_add(sv, p_mul_bmx(t1, tR2));
        sv = p_mul_xma(t1, tL1);
        t2 = p_scal(N2, R3c);
        N2 = p_add(sv, p_mul_bmx(t2, tR3));
        N3 = p_mul_xma(t2, tL0);

        // dot with control points; invalid basis indices get cp = 0
        float cpv[4];
        #pragma unroll
        for (int r = 0; r < 4; ++r) {
            int i = iv - 3 + r;
            cpv[r] = (i >= 0 && i <= 7) ? cp[od * NS + i] : 0.f;
        }
        sp = p_add(p_add(p_scal(N0, cpv[0]), p_scal(N1, cpv[1])),
                   p_add(p_scal(N2, cpv[2]), p_scal(N3, cpv[3])));
    }

    // fold activation linear parts: out += 0.1*(w3*x - w1)
    float w1 = aw[od * 4 + 1];
    float w3 = aw[od * 4 + 3];
    sp.c0 -= 0.1f * w1;
    sp.c1 += 0.1f * w3;

    g_rec[flat] = make_float4(sp.c0, sp.c1, sp.c2, sp.c3);
}

// ---------- main kernel ----------
// grid (2048/64, 64), block 256 = 64 bn-lanes x 4 d-quarters
__global__ __launch_bounds__(256)
void kan_main(const float* __restrict__ x,      // (4,512,64)
              const float* __restrict__ knots,  // (64,64,12)
              const float* __restrict__ aw,     // (64,64,4)
              float* __restrict__ out)          // (4,64,512)
{
    __shared__ float s_red[4][64];

    const int o   = blockIdx.y;
    const int bnl = threadIdx.x & 63;
    const int dq  = threadIdx.x >> 6;
    const int bn  = blockIdx.x * 64 + bnl;
    const int d0  = dq * 16;

    // 16 x-values for this thread's d-slice (4x dwordx4)
    const float4* xp = (const float4*)(x + bn * D_IN + d0);
    float4 xa = xp[0], xb = xp[1], xc = xp[2], xd = xp[3];
    float xs[16] = {xa.x, xa.y, xa.z, xa.w, xb.x, xb.y, xb.z, xb.w,
                    xc.x, xc.y, xc.z, xc.w, xd.x, xd.y, xd.z, xd.w};

    float acc  = 0.f;   // spline + folded linear parts
    float aacc = 0.f;   // relu/tanh/sigmoid parts (pre-0.1 scale)

    #pragma unroll
    for (int i = 0; i < 16; ++i) {
        const int d  = d0 + i;
        const int od = o * D_IN + d;
        const float xv = xs[i];

        // interval index = #{j : x >= t[j]}  (0 or 12 -> out of range, zero record)
        const float* __restrict__ kt = knots + od * NK;   // uniform address -> s_load
        int cnt = 0;
        #pragma unroll
        for (int j = 0; j < NK; ++j) cnt += (xv >= kt[j]) ? 1 : 0;

        // cubic eval
        float4 cf = g_rec[od * NREC + cnt];
        acc += ((cf.w * xv + cf.z) * xv + cf.y) * xv + cf.x;

        // activations: v = e^{-x}; tanh = 2/(1+v^2)-1 (const folded); sig = 1/(1+v)
        float w0 = aw[od * 4 + 0];   // uniform -> s_load
        float w1 = aw[od * 4 + 1];
        float w2 = aw[od * 4 + 2];
        float v  = __expf(-xv);
        float Ra = __builtin_amdgcn_rcpf(1.f + v * v);
        float Rb = __builtin_amdgcn_rcpf(1.f + v);
        aacc += fmaxf(xv, 0.f) * w0 + (2.f * w1) * Ra + w2 * Rb;
    }

    s_red[dq][bnl] = acc + 0.1f * aacc;
    __syncthreads();

    if (dq == 0) {
        float r = s_red[0][bnl] + s_red[1][bnl] + s_red[2][bnl] + s_red[3][bnl];
        const int b = bn >> 9;
        const int n = bn & 511;
        out[((b * D_OUT + o) << 9) | n] = r;
    }
}

extern "C" void kernel_launch(void* const* d_in, const int* in_sizes, int n_in,
                              void* d_out, int out_size, void* d_ws, size_t ws_size,
                              hipStream_t stream) {
    const float* x     = (const float*)d_in[0];  // (4,512,64)
    const float* cp    = (const float*)d_in[1];  // (64,64,8)
    const float* knots = (const float*)d_in[2];  // (64,64,12)
    const float* aw    = (const float*)d_in[3];  // (64,64,4)
    float* out = (float*)d_out;                  // (4,64,512)

    const int nrec = D_OUT * D_IN * NREC;        // 53248
    kan_prep<<<(nrec + 255) / 256, 256, 0, stream>>>(cp, knots, aw);

    dim3 grid(2048 / 64, D_OUT);                 // (32, 64)
    kan_main<<<grid, 256, 0, stream>>>(x, knots, aw, out);
}

// Round 3
// 26.283 us; speedup vs baseline: 3.1419x; 1.3049x over previous
//
#include <hip/hip_runtime.h>

#define D_IN 64
#define D_OUT 64
#define NS 8        // NUM_SPLINES
#define NK 12       // knots per (o,d)
#define NREC 13     // interval records: idx = count(x >= t[j]) in [0,12]
#define KAN_EPS 1e-8f

// per-(o,d,interval) cubic coeffs of sum_s B3_s(x)*cp_s + 0.1*(w3*x - w1)
__device__ float4 g_rec[D_OUT * D_IN * NREC];   // 832 KB
__device__ float4 g_m1[D_OUT * D_IN];           // {t0, inv_h, flag, w0}
__device__ float2 g_m2[D_OUT * D_IN];           // {2*w1, w2}

// ---------- polynomial helpers ----------
struct P4 { float c0, c1, c2, c3; };
__device__ inline P4 p_scal(P4 p, float s) { return {p.c0*s, p.c1*s, p.c2*s, p.c3*s}; }
__device__ inline P4 p_add(P4 a, P4 b) { return {a.c0+b.c0, a.c1+b.c1, a.c2+b.c2, a.c3+b.c3}; }
__device__ inline P4 p_mul_xma(P4 p, float a) { return {-a*p.c0, p.c0 - a*p.c1, p.c1 - a*p.c2, p.c2 - a*p.c3}; }
__device__ inline P4 p_mul_bmx(P4 p, float b) { return {b*p.c0, b*p.c1 - p.c0, b*p.c2 - p.c1, b*p.c3 - p.c2}; }

// ---------- fused prep: records + meta + acts table ----------
// blocks [0,208): record build (one thread per (o,d,iv13))
// blocks [208,224): meta build (one thread per od)
// blocks [224,736): acts table (one thread per (d,bn))
__global__ __launch_bounds__(256)
void kan_prep_all(const float* __restrict__ cp,     // (64,64,8)
                  const float* __restrict__ knots,  // (64,64,12)
                  const float* __restrict__ aw,     // (64,64,4)
                  const float* __restrict__ x,      // (4,512,64)
                  float4* __restrict__ acts)        // ws: [64][2048]
{
    const int blk = blockIdx.x;
    const int tid = threadIdx.x;

    if (blk < 208) {
        // ---- piecewise-cubic records ----
        int flat = blk * 256 + tid;          // < 53248 exactly
        int iv13 = flat % NREC;
        int od   = flat / NREC;

        float t[NK];
        #pragma unroll
        for (int j = 0; j < NK; ++j) t[j] = knots[od * NK + j];
        auto tk = [&](int j) -> float {
            if (j < 0)  return t[0]  + (float)j;
            if (j > 11) return t[11] + (float)(j - 11);
            return t[j];
        };

        P4 sp = {0.f, 0.f, 0.f, 0.f};
        int iv = iv13 - 1;
        if (iv >= 0 && iv <= 10) {
            float tL0 = tk(iv),   tL1 = tk(iv-1), tL2 = tk(iv-2);
            float tR1 = tk(iv+1), tR2 = tk(iv+2), tR3 = tk(iv+3);
            float R1  = 1.f / (tR1 - tL0 + KAN_EPS);
            float R2a = 1.f / (tR1 - tL1 + KAN_EPS);
            float R2b = 1.f / (tR2 - tL0 + KAN_EPS);
            float R3a = 1.f / (tR1 - tL2 + KAN_EPS);
            float R3b = 1.f / (tR2 - tL1 + KAN_EPS);
            float R3c = 1.f / (tR3 - tL0 + KAN_EPS);

            P4 N0 = {1.f, 0.f, 0.f, 0.f}, N1, N2, N3, t0p, t1p, t2p, sv;
            t0p = p_scal(N0, R1);
            N0 = p_mul_bmx(t0p, tR1);
            N1 = p_mul_xma(t0p, tL0);
            t0p = p_scal(N0, R2a);
            N0 = p_mul_bmx(t0p, tR1);
            sv = p_mul_xma(t0p, tL1);
            t1p = p_scal(N1, R2b);
            N1 = p_add(sv, p_mul_bmx(t1p, tR2));
            N2 = p_mul_xma(t1p, tL0);
            t0p = p_scal(N0, R3a);
            N0 = p_mul_bmx(t0p, tR1);
            sv = p_mul_xma(t0p, tL2);
            t1p = p_scal(N1, R3b);
            N1 = p_add(sv, p_mul_bmx(t1p, tR2));
            sv = p_mul_xma(t1p, tL1);
            t2p = p_scal(N2, R3c);
            N2 = p_add(sv, p_mul_bmx(t2p, tR3));
            N3 = p_mul_xma(t2p, tL0);

            float cpv[4];
            #pragma unroll
            for (int r = 0; r < 4; ++r) {
                int i = iv - 3 + r;
                cpv[r] = (i >= 0 && i <= 7) ? cp[od * NS + i] : 0.f;
            }
            sp = p_add(p_add(p_scal(N0, cpv[0]), p_scal(N1, cpv[1])),
                       p_add(p_scal(N2, cpv[2]), p_scal(N3, cpv[3])));
        }
        float w1 = aw[od * 4 + 1];
        float w3 = aw[od * 4 + 3];
        sp.c0 -= 0.1f * w1;
        sp.c1 += 0.1f * w3;
        g_rec[flat] = make_float4(sp.c0, sp.c1, sp.c2, sp.c3);

    } else if (blk < 224) {
        // ---- per-od meta: uniform-grid detect + act weights ----
        int od = (blk - 208) * 256 + tid;    // < 4096 exactly
        const float* t = knots + od * NK;
        float t0 = t[0];
        float h  = (t[11] - t0) * (1.0f / 11.0f);
        bool uni = (h > 0.0f);
        #pragma unroll
        for (int j = 0; j < 11; ++j)
            uni = uni && (fabsf((t[j + 1] - t[j]) - h) <= fmaxf(1e-6f, 1e-4f * fabsf(h)));
        float w0 = aw[od * 4 + 0];
        float w1 = aw[od * 4 + 1];
        float w2 = aw[od * 4 + 2];
        g_m1[od] = make_float4(t0, uni ? 1.0f / h : 0.0f, uni ? 1.0f : 0.0f, w0);
        g_m2[od] = make_float2(2.0f * w1, w2);

    } else {
        // ---- acts table: [d][bn] = {relu, 1/(1+v^2), 1/(1+v), 0}, v=e^{-x} ----
        int idx = (blk - 224) * 256 + tid;   // < 131072 exactly
        int d  = idx >> 11;
        int bn = idx & 2047;
        float xv = x[bn * D_IN + d];
        float v  = __expf(-xv);
        float Ra = __builtin_amdgcn_rcpf(1.f + v * v);
        float Rb = __builtin_amdgcn_rcpf(1.f + v);
        acts[idx] = make_float4(fmaxf(xv, 0.f), Ra, Rb, 0.f);
    }
}

// ---------- main kernel ----------
// grid (32, 64), block 256 = 64 bn-lanes x 4 d-quarters
__global__ __launch_bounds__(256)
void kan_main(const float* __restrict__ x,      // (4,512,64)
              const float* __restrict__ knots,  // (64,64,12)
              const float4* __restrict__ acts,  // ws: [64][2048]
              float* __restrict__ out)          // (4,64,512)
{
    __shared__ float s_red[4][64];

    const int o   = blockIdx.y;
    const int bnl = threadIdx.x & 63;
    const int dq  = threadIdx.x >> 6;
    const int bn  = blockIdx.x * 64 + bnl;
    const int d0  = dq * 16;

    const float4* xp = (const float4*)(x + bn * D_IN + d0);
    float4 xa = xp[0], xb = xp[1], xc = xp[2], xd = xp[3];
    float xs[16] = {xa.x, xa.y, xa.z, xa.w, xb.x, xb.y, xb.z, xb.w,
                    xc.x, xc.y, xc.z, xc.w, xd.x, xd.y, xd.z, xd.w};

    float acc  = 0.f;
    float aacc = 0.f;

    #pragma unroll
    for (int i = 0; i < 16; ++i) {
        const int d  = d0 + i;
        const int od = __builtin_amdgcn_readfirstlane(o * D_IN + d); // wave-uniform -> SGPR
        const float xv = xs[i];

        const float4 m1 = g_m1[od];
        int cnt;
        if (__builtin_amdgcn_readfirstlane(__float_as_int(m1.z))) {
            // uniform-knot fast path: cnt = clamp(floor((x-t0)/h)+1, 0, 12)
            float u  = (xv - m1.x) * m1.y;
            float cf = fminf(fmaxf(floorf(u) + 1.0f, 0.0f), 12.0f);
            cnt = (int)cf;
        } else {
            const float* __restrict__ kt = knots + od * NK;
            cnt = 0;
            #pragma unroll
            for (int j = 0; j < NK; ++j) cnt += (xv >= kt[j]) ? 1 : 0;
        }

        const float4 cf4 = g_rec[od * NREC + cnt];
        acc += ((cf4.w * xv + cf4.z) * xv + cf4.y) * xv + cf4.x;

        const float2 m2 = g_m2[od];
        const float4 a  = acts[(d << 11) + bn];
        aacc += a.x * m1.w + a.y * m2.x + a.z * m2.y;
    }

    s_red[dq][bnl] = acc + 0.1f * aacc;
    __syncthreads();

    if (dq == 0) {
        float r = s_red[0][bnl] + s_red[1][bnl] + s_red[2][bnl] + s_red[3][bnl];
        const int b = bn >> 9;
        const int n = bn & 511;
        out[((b * D_OUT + o) << 9) | n] = r;
    }
}

extern "C" void kernel_launch(void* const* d_in, const int* in_sizes, int n_in,
                              void* d_out, int out_size, void* d_ws, size_t ws_size,
                              hipStream_t stream) {
    const float* x     = (const float*)d_in[0];  // (4,512,64)
    const float* cp    = (const float*)d_in[1];  // (64,64,8)
    const float* knots = (const float*)d_in[2];  // (64,64,12)
    const float* aw    = (const float*)d_in[3];  // (64,64,4)
    float* out = (float*)d_out;                  // (4,64,512)
    float4* acts = (float4*)d_ws;                // 2 MB

    kan_prep_all<<<736, 256, 0, stream>>>(cp, knots, aw, x, acts);

    dim3 grid(2048 / 64, D_OUT);                 // (32, 64)
    kan_main<<<grid, 256, 0, stream>>>(x, knots, acts, out);
}